// Round 26
// baseline (108.730 us; speedup 1.0000x reference)
//
#include <hip/hip_runtime.h>
#include <hip/hip_bf16.h>
#include <math.h>

#define C_CLASSES 100000
#define EMBED     384
#define BATCH     512
#define S_SCALE   64.0f
#define COS_M_    0.8775825618903728f
#define SIN_M_    0.479425538604203f
#define TH_       (-0.8775825618903728f)
#define MM_       0.2397127693021015f
#define EPS_      1e-7f
#define LOG2E_    1.4426950408889634f
#define LN2_      0.6931471805599453f
#define BIGZ_     92.33261191693459f      /* 64 * log2(e) */
#define SK1_      92.33248f               /* fp32(S * log2(e)) */

#define CT    160
#define NCH   625                          // 100000 / 160 EXACT — no tail

typedef __attribute__((ext_vector_type(8))) short bf16x8;
typedef __attribute__((ext_vector_type(4))) float f32x4;

__device__ inline ushort f2bf(float f) {
    unsigned u = __float_as_uint(f);
    unsigned r = (u + 0x7fffu + ((u >> 16) & 1u)) >> 16;   // RNE
    return (ushort)r;
}

__device__ inline ushort cvt_bf(float f) {       // native path (v_cvt_pk-able)
    __hip_bfloat16 h = __float2bfloat16(f);
    return *(ushort*)&h;
}

// ---------------------------------------------------------------------------
// Kernel 0: convert E to bf16, packed in MFMA A-fragment order:
//   eP[((tile*12 + ks)*64 + lane)*8 + j] = bf16(E[tile*16 + (lane&15)]
//                                               [ks*32 + (lane>>4)*8 + j])
// ---------------------------------------------------------------------------
__global__ __launch_bounds__(256)
void cvt_pack_e(const float* __restrict__ emb, ushort* __restrict__ eP)
{
    int t = blockIdx.x * 256 + threadIdx.x;      // 0 .. 24575
    int lane = t & 63;
    int grp  = t >> 6;                           // tile*12 + ks
    int tile = grp / 12, ks = grp % 12;
    int lr = lane & 15, lg = lane >> 4;
    int row = tile * 16 + lr;
    int col = ks * 32 + lg * 8;
    const float4* src = (const float4*)(emb + (size_t)row * EMBED + col);
    float4 v0 = src[0], v1 = src[1];
    ushort4 o0, o1;
    o0.x = f2bf(v0.x); o0.y = f2bf(v0.y); o0.z = f2bf(v0.z); o0.w = f2bf(v0.w);
    o1.x = f2bf(v1.x); o1.y = f2bf(v1.y); o1.z = f2bf(v1.z); o1.w = f2bf(v1.w);
    ((ushort4*)eP)[t * 2]     = o0;
    ((ushort4*)eP)[t * 2 + 1] = o1;
}

// ---------------------------------------------------------------------------
// Staging helpers: pass h stages classes h*64 .. (h<2 ? +63 : +31)
// (16 lanes/row; pass 2 uses threads 0..511 only).
// ---------------------------------------------------------------------------
__device__ __forceinline__ void load_w(const float* __restrict__ weight,
                                       int c0, int h, int tid, float4 wv[6])
{
    if (h < 2 || tid < 512) {
        const int c = h * 64 + (tid >> 4);
        const float4* s = (const float4*)(weight + (size_t)(c0 + c) * EMBED)
                        + (tid & 15);
        wv[0] = s[0];  wv[1] = s[16]; wv[2] = s[32];
        wv[3] = s[48]; wv[4] = s[64]; wv[5] = s[80];
    }
}

__device__ __forceinline__ void pack_w(ushort* __restrict__ Bl,
                                       int h, int tid, const float4 wv[6])
{
    if (h < 2 || tid < 512) {
        const int c = h * 64 + (tid >> 4);
        const int p = tid & 15;
        float ss = 0.f;
        #pragma unroll
        for (int i = 0; i < 6; ++i)
            ss += wv[i].x * wv[i].x + wv[i].y * wv[i].y
                + wv[i].z * wv[i].z + wv[i].w * wv[i].w;
        ss += __shfl_xor(ss, 1, 64);
        ss += __shfl_xor(ss, 2, 64);
        ss += __shfl_xor(ss, 4, 64);
        ss += __shfl_xor(ss, 8, 64);
        const float inv = (ss > 0.f) ? rsqrtf(ss) : 0.f;
        const int t2 = c >> 4, cl = c & 15;
        #pragma unroll
        for (int i = 0; i < 6; ++i) {
            int q   = p + 16 * i;            // quad index 0..95
            int ks  = q >> 3;
            int lgp = (q >> 1) & 3;
            int jo  = (q & 1) * 4;
            ushort4 o;
            o.x = cvt_bf(wv[i].x * inv); o.y = cvt_bf(wv[i].y * inv);
            o.z = cvt_bf(wv[i].z * inv); o.w = cvt_bf(wv[i].w * inv);
            int ei = (((t2 * 12 + ks) * 64) + cl + 16 * lgp) * 8 + jo;
            ei ^= (lgp & 3) << 4;            // bank swizzle (write)
            *(ushort4*)&Bl[ei] = o;
        }
    }
}

// ---------------------------------------------------------------------------
// One N-group MFMA pass + immediate partial epilogue into zsum.
// BASE = first Ntile, GSZ = tiles in group. acc is only [2][GSZ] (<=32 regs).
// ---------------------------------------------------------------------------
template<int BASE, int GSZ>
__device__ __forceinline__ void mfma_pass(
    const ushort* __restrict__ abase, const ushort* __restrict__ Bl,
    int bxo, int l, int lr, int lg, int wid, int c0,
    const int* __restrict__ labL, float zsum[2][4],
    float* __restrict__ zlabel)
{
    f32x4 acc[2][GSZ];
    #pragma unroll
    for (int mt = 0; mt < 2; ++mt)
        #pragma unroll
        for (int j = 0; j < GSZ; ++j)
            acc[mt][j] = (f32x4){0.f, 0.f, 0.f, 0.f};

    #pragma unroll
    for (int ks = 0; ks < 12; ++ks) {
        bf16x8 a0 = *(const bf16x8*)(abase + (0 * 12 + ks) * 512);
        bf16x8 a1 = *(const bf16x8*)(abase + (1 * 12 + ks) * 512);
        #pragma unroll
        for (int j = 0; j < GSZ; ++j) {
            int ei = (((BASE + j) * 12 + ks) * 64 + l) * 8;
            bf16x8 b = *(const bf16x8*)&Bl[ei ^ bxo];
            acc[0][j] = __builtin_amdgcn_mfma_f32_16x16x32_bf16(
                a0, b, acc[0][j], 0, 0, 0);
            acc[1][j] = __builtin_amdgcn_mfma_f32_16x16x32_bf16(
                a1, b, acc[1][j], 0, 0, 0);
        }
    }

    #pragma unroll
    for (int mt = 0; mt < 2; ++mt) {
        #pragma unroll
        for (int rg = 0; rg < 4; ++rg) {
            const int r   = wid * 32 + mt * 16 + lg * 4 + rg;   // 0..511
            const int lab = labL[r];
            float s = 0.f;
            #pragma unroll
            for (int j = 0; j < GSZ; ++j) {
                float cv = __builtin_amdgcn_fmed3f(acc[mt][j][rg],
                                                   -1.f + EPS_, 1.f - EPS_);
                s += exp2f(fmaf(cv, SK1_, -BIGZ_));
            }
            zsum[mt][rg] += s;
            int off = lab - (c0 + BASE * 16);
            if (((unsigned)off < (unsigned)(GSZ * 16)) && ((off & 15) == lr)) {
                int ntl = off >> 4;                  // 0..GSZ-1
                float cv = acc[mt][0][rg];
                #pragma unroll
                for (int j = 1; j < GSZ; ++j)
                    cv = (ntl == j) ? acc[mt][j][rg] : cv;
                cv = __builtin_amdgcn_fmed3f(cv, -1.f + EPS_, 1.f - EPS_);
                float plain = exp2f(fmaf(cv, SK1_, -BIGZ_));
                float zm;
                if (cv > TH_) {
                    float sv = sqrtf(fmaxf(1.f - cv * cv, 0.f));
                    zm = S_SCALE * (cv * COS_M_ - sv * SIN_M_);
                } else {
                    zm = S_SCALE * (cv - MM_);
                }
                zsum[mt][rg] += exp2f(fmaf(zm, LOG2E_, -BIGZ_)) - plain;
                zlabel[r] = zm;
            }
        }
    }
}

// ---------------------------------------------------------------------------
// Kernel 1: CT=160 fused kernel with PASS-PIPELINED staging:
// pass h+1's W loads are issued before pass h's MFMA and consumed after —
// HBM latency hides under MFMA+epilogue instead of convoying behind a
// barrier. acc is only 32 regs per pass (results fold into zsum), so the
// in-flight wv[6] fits the (1024,4) budget. grid = 625 x 1024, LDS 122 KB.
// ---------------------------------------------------------------------------
__global__ __launch_bounds__(1024, 4)
void arc_pipe160(const ushort* __restrict__ eP, const int* __restrict__ labels,
                 const float* __restrict__ weight,
                 float* __restrict__ psum, float* __restrict__ zlabel)
{
    __shared__ ushort Bl[(CT / 16) * 12 * 512];    // 61440 ushorts = 122880 B
    __shared__ int    labL[BATCH];

    const int tid = threadIdx.x;

    // bijective XCD-aware swizzle (m204 form)
    const int orig = blockIdx.x;
    const int xcd  = orig & 7;
    const int qq   = NCH >> 3, rr = NCH & 7;       // 78, 1
    const int blk  = (xcd < rr ? xcd * (qq + 1)
                               : rr * (qq + 1) + (xcd - rr) * qq) + (orig >> 3);
    const int c0   = blk * CT;

    if (tid < BATCH) labL[tid] = labels[tid];

    const int wid = tid >> 6, l = tid & 63;
    const int lr  = l & 15,  lg = l >> 4;
    const int bxo = (lg & 3) << 4;                 // bank swizzle (read)
    const ushort* abase = eP + ((size_t)(wid * 2) * 12 * 64 + l) * 8;

    float zsum[2][4];
    #pragma unroll
    for (int mt = 0; mt < 2; ++mt)
        #pragma unroll
        for (int rg = 0; rg < 4; ++rg) zsum[mt][rg] = 0.f;

    float4 wv[6];

    // ---- prologue: stage pass 0 ----
    load_w(weight, c0, 0, tid, wv);
    pack_w(Bl, 0, tid, wv);
    __syncthreads();

    // ---- pass 0: issue loads(1) || MFMA nt 0..3 ----
    load_w(weight, c0, 1, tid, wv);
    __builtin_amdgcn_sched_barrier(0);             // pin load issue early
    mfma_pass<0, 4>(abase, Bl, bxo, l, lr, lg, wid, c0, labL, zsum, zlabel);
    pack_w(Bl, 1, tid, wv);
    __syncthreads();

    // ---- pass 1: issue loads(2) || MFMA nt 4..7 ----
    load_w(weight, c0, 2, tid, wv);
    __builtin_amdgcn_sched_barrier(0);
    mfma_pass<4, 4>(abase, Bl, bxo, l, lr, lg, wid, c0, labL, zsum, zlabel);
    pack_w(Bl, 2, tid, wv);
    __syncthreads();

    // ---- pass 2: MFMA nt 8..9 ----
    mfma_pass<8, 2>(abase, Bl, bxo, l, lr, lg, wid, c0, labL, zsum, zlabel);

    // ---- final: 16-lane reduce of zsum, one partial per row ----
    #pragma unroll
    for (int mt = 0; mt < 2; ++mt) {
        #pragma unroll
        for (int rg = 0; rg < 4; ++rg) {
            const int r = wid * 32 + mt * 16 + lg * 4 + rg;
            float s = zsum[mt][rg];
            s += __shfl_xor(s, 1, 64);
            s += __shfl_xor(s, 2, 64);
            s += __shfl_xor(s, 4, 64);
            s += __shfl_xor(s, 8, 64);
            if (lr == 0) psum[(size_t)blk * BATCH + r] = s;
        }
    }
}

// ---------------------------------------------------------------------------
// Kernel 2: sum 625 chunk-partials per row -> row loss
// ---------------------------------------------------------------------------
__global__ __launch_bounds__(256)
void arc_reduce(const float* __restrict__ psum, const float* __restrict__ zlabel,
                float* __restrict__ rowloss)
{
    const int r = blockIdx.x;
    const int tid = threadIdx.x;
    float s = 0.f;
    for (int k = tid; k < NCH; k += 256)
        s += psum[(size_t)k * BATCH + r];
    #pragma unroll
    for (int d = 1; d < 64; d <<= 1) s += __shfl_xor(s, d, 64);
    __shared__ float ssh[4];
    if ((tid & 63) == 0) ssh[tid >> 6] = s;
    __syncthreads();
    if (tid == 0) {
        float t = ssh[0] + ssh[1] + ssh[2] + ssh[3];
        rowloss[r] = LN2_ * (BIGZ_ + log2f(t)) - zlabel[r];
    }
}

// ---------------------------------------------------------------------------
// Kernel 3: mean over rows
// ---------------------------------------------------------------------------
__global__ __launch_bounds__(512)
void arc_mean(const float* __restrict__ rowloss, float* __restrict__ out)
{
    const int tid = threadIdx.x;
    float v = rowloss[tid];
    #pragma unroll
    for (int d = 1; d < 64; d <<= 1) v += __shfl_xor(v, d, 64);
    __shared__ float sv[8];
    if ((tid & 63) == 0) sv[tid >> 6] = v;
    __syncthreads();
    if (tid == 0) {
        float t = 0.f;
        #pragma unroll
        for (int w = 0; w < 8; ++w) t += sv[w];
        out[0] = t / (float)BATCH;
    }
}

extern "C" void kernel_launch(void* const* d_in, const int* in_sizes, int n_in,
                              void* d_out, int out_size, void* d_ws, size_t ws_size,
                              hipStream_t stream)
{
    (void)in_sizes; (void)n_in; (void)out_size; (void)ws_size;
    const float* emb    = (const float*)d_in[0];
    const int*   labels = (const int*)d_in[1];
    const float* weight = (const float*)d_in[2];
    float* out = (float*)d_out;

    float*  psum    = (float*)d_ws;                    // [NCH][BATCH]  1.28 MB
    float*  zlabel  = psum + (size_t)NCH * BATCH;      // [BATCH]
    float*  rowloss = zlabel + BATCH;                  // [BATCH]
    ushort* eP      = (ushort*)(rowloss + BATCH);      // packed bf16 E frags

    cvt_pack_e<<<(BATCH * EMBED / 8) / 256, 256, 0, stream>>>(emb, eP);
    arc_pipe160<<<NCH, 1024, 0, stream>>>(eP, labels, weight, psum, zlabel);
    arc_reduce<<<BATCH, 256, 0, stream>>>(psum, zlabel, rowloss);
    arc_mean<<<1, 512, 0, stream>>>(rowloss, out);
}

// Round 27
// 84.674 us; speedup vs baseline: 1.2841x; 1.2841x over previous
//
#include <hip/hip_runtime.h>
#include <hip/hip_bf16.h>
#include <math.h>

#define C_CLASSES 100000
#define EMBED     384
#define BATCH     512
#define S_SCALE   64.0f
#define COS_M_    0.8775825618903728f
#define SIN_M_    0.479425538604203f
#define TH_       (-0.8775825618903728f)
#define MM_       0.2397127693021015f
#define EPS_      1e-7f
#define LOG2E_    1.4426950408889634f
#define LN2_      0.6931471805599453f
#define BIGZ_     92.33261191693459f      /* 64 * log2(e) */
#define SK1_      92.33248f               /* fp32(S * log2(e)) */

#define CT    160
#define NCH   625                          // 100000 / 160 EXACT — no tail at all

typedef __attribute__((ext_vector_type(8))) short bf16x8;
typedef __attribute__((ext_vector_type(4))) float f32x4;

__device__ inline ushort f2bf(float f) {
    unsigned u = __float_as_uint(f);
    unsigned r = (u + 0x7fffu + ((u >> 16) & 1u)) >> 16;   // RNE
    return (ushort)r;
}

__device__ inline ushort cvt_bf(float f) {       // native path (v_cvt_pk-able)
    __hip_bfloat16 h = __float2bfloat16(f);
    return *(ushort*)&h;
}

// ---------------------------------------------------------------------------
// Kernel 0: convert E to bf16, packed in MFMA A-fragment order:
//   eP[((tile*12 + ks)*64 + lane)*8 + j] = bf16(E[tile*16 + (lane&15)]
//                                               [ks*32 + (lane>>4)*8 + j])
// ---------------------------------------------------------------------------
__global__ __launch_bounds__(256)
void cvt_pack_e(const float* __restrict__ emb, ushort* __restrict__ eP)
{
    int t = blockIdx.x * 256 + threadIdx.x;      // 0 .. 24575
    int lane = t & 63;
    int grp  = t >> 6;                           // tile*12 + ks
    int tile = grp / 12, ks = grp % 12;
    int lr = lane & 15, lg = lane >> 4;
    int row = tile * 16 + lr;
    int col = ks * 32 + lg * 8;
    const float4* src = (const float4*)(emb + (size_t)row * EMBED + col);
    float4 v0 = src[0], v1 = src[1];
    ushort4 o0, o1;
    o0.x = f2bf(v0.x); o0.y = f2bf(v0.y); o0.z = f2bf(v0.z); o0.w = f2bf(v0.w);
    o1.x = f2bf(v1.x); o1.y = f2bf(v1.y); o1.z = f2bf(v1.z); o1.w = f2bf(v1.w);
    ((ushort4*)eP)[t * 2]     = o0;
    ((ushort4*)eP)[t * 2 + 1] = o1;
}

// ---------------------------------------------------------------------------
// Kernel 1: CT=160 fused kernel (best-known configuration, rounds 22/25).
// grid = 625 x 1024 thr (16 waves, 1 block/CU, LDS 125 KB).
//  phase 1: three passes (64+64+32 rows, 16 lanes/row, wv[6] transient,
//           fence after each); sumsq butterfly; scale -> bf16 ->
//           fragment-packed, bank-swizzled LDS (120 KB).
//  phase 2: MFMA 16 waves x (2 Mtiles x 10 Ntiles x 12 ks); A-frags from
//           L2-resident eP (240 MB total L2-A).
//  phase 3: fixed-max LSE over 10 nt (fmed3 clamp) + rare margin fixup.
// ---------------------------------------------------------------------------
__global__ __launch_bounds__(1024, 4)
void arc_fused160(const ushort* __restrict__ eP, const int* __restrict__ labels,
                  const float* __restrict__ weight,
                  float* __restrict__ psum, float* __restrict__ zlabel)
{
    __shared__ ushort Bl[(CT / 16) * 12 * 512];    // 61440 ushorts = 122880 B
    __shared__ int    labL[BATCH];

    const int tid = threadIdx.x;

    // bijective XCD-aware swizzle (m204 form)
    const int orig = blockIdx.x;
    const int xcd  = orig & 7;
    const int qq   = NCH >> 3, rr = NCH & 7;       // 78, 1
    const int blk  = (xcd < rr ? xcd * (qq + 1)
                               : rr * (qq + 1) + (xcd - rr) * qq) + (orig >> 3);
    const int c0   = blk * CT;

    if (tid < BATCH) labL[tid] = labels[tid];

    // ---- phase 1: three passes (64 + 64 + 32 rows, 16 lanes/row) ----
    {
        const int p = tid & 15;              // 16 lanes per class
        #pragma unroll
        for (int h = 0; h < 3; ++h) {
            if (h < 2 || tid < 512) {
                const int c = h * 64 + (tid >> 4);       // class 0..159
                const float4* src =
                    (const float4*)(weight + (size_t)(c0 + c) * EMBED) + p;

                float4 wv[6];
                float ss = 0.f;
                #pragma unroll
                for (int i = 0; i < 6; ++i) {
                    wv[i] = src[16 * i];
                    ss += wv[i].x * wv[i].x + wv[i].y * wv[i].y
                        + wv[i].z * wv[i].z + wv[i].w * wv[i].w;
                }
                ss += __shfl_xor(ss, 1, 64);
                ss += __shfl_xor(ss, 2, 64);
                ss += __shfl_xor(ss, 4, 64);
                ss += __shfl_xor(ss, 8, 64);
                const float inv = (ss > 0.f) ? rsqrtf(ss) : 0.f;

                const int t2 = c >> 4, cl = c & 15;      // t2 in 0..9
                #pragma unroll
                for (int i = 0; i < 6; ++i) {
                    int q   = p + 16 * i;    // quad index 0..95 (k = 4q..4q+3)
                    int ks  = q >> 3;
                    int lgp = (q >> 1) & 3;
                    int jo  = (q & 1) * 4;
                    ushort4 o;
                    o.x = cvt_bf(wv[i].x * inv); o.y = cvt_bf(wv[i].y * inv);
                    o.z = cvt_bf(wv[i].z * inv); o.w = cvt_bf(wv[i].w * inv);
                    int ei = (((t2 * 12 + ks) * 64) + cl + 16 * lgp) * 8 + jo;
                    ei ^= (lgp & 3) << 4;                 // bank swizzle (write)
                    *(ushort4*)&Bl[ei] = o;
                }
            }
            __builtin_amdgcn_sched_barrier(0);            // anti-hoist fence
        }
    }
    __syncthreads();     // packed B + labL ready

    // ---- phase 2: MFMA, 16 waves x (2 Mtiles x 10 Ntiles), K=384 ----
    const int wid = tid >> 6, l = tid & 63;
    const int lr  = l & 15,  lg = l >> 4;
    const int bxo = (lg & 3) << 4;                        // bank swizzle (read)

    // wave w owns rows w*32 .. w*32+31 (tiles w*2, w*2+1)
    const ushort* abase = eP + ((size_t)(wid * 2) * 12 * 64 + l) * 8;

    f32x4 acc[2][10];
    #pragma unroll
    for (int mt = 0; mt < 2; ++mt)
        #pragma unroll
        for (int nt = 0; nt < 10; ++nt)
            acc[mt][nt] = (f32x4){0.f, 0.f, 0.f, 0.f};

    #pragma unroll
    for (int ks = 0; ks < 12; ++ks) {
        bf16x8 a0 = *(const bf16x8*)(abase + (0 * 12 + ks) * 512);
        bf16x8 a1 = *(const bf16x8*)(abase + (1 * 12 + ks) * 512);
        #pragma unroll
        for (int nt = 0; nt < 10; ++nt) {
            int ei = ((nt * 12 + ks) * 64 + l) * 8;
            bf16x8 b = *(const bf16x8*)&Bl[ei ^ bxo];
            acc[0][nt] = __builtin_amdgcn_mfma_f32_16x16x32_bf16(
                a0, b, acc[0][nt], 0, 0, 0);
            acc[1][nt] = __builtin_amdgcn_mfma_f32_16x16x32_bf16(
                a1, b, acc[1][nt], 0, 0, 0);
        }
    }

    // ---- phase 3: fixed-max LSE over 10 nt + rare margin fixup ----
    #pragma unroll
    for (int mt = 0; mt < 2; ++mt) {
        #pragma unroll
        for (int rg = 0; rg < 4; ++rg) {
            const int r   = wid * 32 + mt * 16 + lg * 4 + rg;   // 0..511
            const int lab = labL[r];
            float acc4 = 0.f;
            #pragma unroll
            for (int nt = 0; nt < 10; ++nt) {
                float cv = __builtin_amdgcn_fmed3f(acc[mt][nt][rg],
                                                   -1.f + EPS_, 1.f - EPS_);
                acc4 += exp2f(fmaf(cv, SK1_, -BIGZ_));
            }
            int off = lab - c0;
            if (((unsigned)off < (unsigned)CT) && ((off & 15) == lr)) {
                int ntl = off >> 4;                  // 0..9
                float cv = acc[mt][0][rg];
                #pragma unroll
                for (int nt = 1; nt < 10; ++nt)
                    cv = (ntl == nt) ? acc[mt][nt][rg] : cv;
                cv = __builtin_amdgcn_fmed3f(cv, -1.f + EPS_, 1.f - EPS_);
                float plain = exp2f(fmaf(cv, SK1_, -BIGZ_));
                float zm;
                if (cv > TH_) {
                    float sv = sqrtf(fmaxf(1.f - cv * cv, 0.f));
                    zm = S_SCALE * (cv * COS_M_ - sv * SIN_M_);
                } else {
                    zm = S_SCALE * (cv - MM_);
                }
                acc4 += exp2f(fmaf(zm, LOG2E_, -BIGZ_)) - plain;
                zlabel[r] = zm;
            }
            acc4 += __shfl_xor(acc4, 1, 64);
            acc4 += __shfl_xor(acc4, 2, 64);
            acc4 += __shfl_xor(acc4, 4, 64);
            acc4 += __shfl_xor(acc4, 8, 64);
            if (lr == 0) psum[(size_t)blk * BATCH + r] = acc4;
        }
    }
}

// ---------------------------------------------------------------------------
// Kernel 2: sum 625 chunk-partials per row -> row loss
// ---------------------------------------------------------------------------
__global__ __launch_bounds__(256)
void arc_reduce(const float* __restrict__ psum, const float* __restrict__ zlabel,
                float* __restrict__ rowloss)
{
    const int r = blockIdx.x;
    const int tid = threadIdx.x;
    float s = 0.f;
    for (int k = tid; k < NCH; k += 256)
        s += psum[(size_t)k * BATCH + r];
    #pragma unroll
    for (int d = 1; d < 64; d <<= 1) s += __shfl_xor(s, d, 64);
    __shared__ float ssh[4];
    if ((tid & 63) == 0) ssh[tid >> 6] = s;
    __syncthreads();
    if (tid == 0) {
        float t = ssh[0] + ssh[1] + ssh[2] + ssh[3];
        rowloss[r] = LN2_ * (BIGZ_ + log2f(t)) - zlabel[r];
    }
}

// ---------------------------------------------------------------------------
// Kernel 3: mean over rows
// ---------------------------------------------------------------------------
__global__ __launch_bounds__(512)
void arc_mean(const float* __restrict__ rowloss, float* __restrict__ out)
{
    const int tid = threadIdx.x;
    float v = rowloss[tid];
    #pragma unroll
    for (int d = 1; d < 64; d <<= 1) v += __shfl_xor(v, d, 64);
    __shared__ float sv[8];
    if ((tid & 63) == 0) sv[tid >> 6] = v;
    __syncthreads();
    if (tid == 0) {
        float t = 0.f;
        #pragma unroll
        for (int w = 0; w < 8; ++w) t += sv[w];
        out[0] = t / (float)BATCH;
    }
}

extern "C" void kernel_launch(void* const* d_in, const int* in_sizes, int n_in,
                              void* d_out, int out_size, void* d_ws, size_t ws_size,
                              hipStream_t stream)
{
    (void)in_sizes; (void)n_in; (void)out_size; (void)ws_size;
    const float* emb    = (const float*)d_in[0];
    const int*   labels = (const int*)d_in[1];
    const float* weight = (const float*)d_in[2];
    float* out = (float*)d_out;

    float*  psum    = (float*)d_ws;                    // [NCH][BATCH]  1.28 MB
    float*  zlabel  = psum + (size_t)NCH * BATCH;      // [BATCH]
    float*  rowloss = zlabel + BATCH;                  // [BATCH]
    ushort* eP      = (ushort*)(rowloss + BATCH);      // packed bf16 E frags

    cvt_pack_e<<<(BATCH * EMBED / 8) / 256, 256, 0, stream>>>(emb, eP);
    arc_fused160<<<NCH, 1024, 0, stream>>>(eP, labels, weight, psum, zlabel);
    arc_reduce<<<BATCH, 256, 0, stream>>>(psum, zlabel, rowloss);
    arc_mean<<<1, 512, 0, stream>>>(rowloss, out);
}

// Round 28
// 82.751 us; speedup vs baseline: 1.3139x; 1.0232x over previous
//
#include <hip/hip_runtime.h>
#include <hip/hip_bf16.h>
#include <math.h>

#define C_CLASSES 100000
#define EMBED     384
#define BATCH     512
#define S_SCALE   64.0f
#define COS_M_    0.8775825618903728f
#define SIN_M_    0.479425538604203f
#define TH_       (-0.8775825618903728f)
#define MM_       0.2397127693021015f
#define EPS_      1e-7f
#define LOG2E_    1.4426950408889634f
#define LN2_      0.6931471805599453f
#define BIGZ_     92.33261191693459f      /* 64 * log2(e) */
#define SK1_      92.33248f               /* fp32(S * log2(e)) */

#define NCHA   512                         // CT=160 blocks: classes 0..81919
#define CB_    81920                       // kernel-B class base
#define NCHB   226                         // CT=80 blocks: 226*80 = 18080
#define NPART  (NCHA + NCHB)               // 738 partials per row

typedef __attribute__((ext_vector_type(8))) short bf16x8;
typedef __attribute__((ext_vector_type(4))) float f32x4;

__device__ inline ushort f2bf(float f) {
    unsigned u = __float_as_uint(f);
    unsigned r = (u + 0x7fffu + ((u >> 16) & 1u)) >> 16;   // RNE
    return (ushort)r;
}

__device__ inline ushort cvt_bf(float f) {       // native path (v_cvt_pk-able)
    __hip_bfloat16 h = __float2bfloat16(f);
    return *(ushort*)&h;
}

// ---------------------------------------------------------------------------
// Kernel 0: convert E to bf16, packed in MFMA A-fragment order:
//   eP[((tile*12 + ks)*64 + lane)*8 + j] = bf16(E[tile*16 + (lane&15)]
//                                               [ks*32 + (lane>>4)*8 + j])
// ---------------------------------------------------------------------------
__global__ __launch_bounds__(256)
void cvt_pack_e(const float* __restrict__ emb, ushort* __restrict__ eP)
{
    int t = blockIdx.x * 256 + threadIdx.x;      // 0 .. 24575
    int lane = t & 63;
    int grp  = t >> 6;                           // tile*12 + ks
    int tile = grp / 12, ks = grp % 12;
    int lr = lane & 15, lg = lane >> 4;
    int row = tile * 16 + lr;
    int col = ks * 32 + lg * 8;
    const float4* src = (const float4*)(emb + (size_t)row * EMBED + col);
    float4 v0 = src[0], v1 = src[1];
    ushort4 o0, o1;
    o0.x = f2bf(v0.x); o0.y = f2bf(v0.y); o0.z = f2bf(v0.z); o0.w = f2bf(v0.w);
    o1.x = f2bf(v1.x); o1.y = f2bf(v1.y); o1.z = f2bf(v1.z); o1.w = f2bf(v1.w);
    ((ushort4*)eP)[t * 2]     = o0;
    ((ushort4*)eP)[t * 2 + 1] = o1;
}

// ---------------------------------------------------------------------------
// Kernel A: CT=160 fused (r22-verbatim body), 512 blocks = EXACTLY 2 rounds.
// ---------------------------------------------------------------------------
__global__ __launch_bounds__(1024, 4)
void arc_fused160(const ushort* __restrict__ eP, const int* __restrict__ labels,
                  const float* __restrict__ weight,
                  float* __restrict__ psum, float* __restrict__ zlabel)
{
    __shared__ ushort Bl[10 * 12 * 512];           // 122880 B
    __shared__ int    labL[BATCH];

    const int tid = threadIdx.x;

    // bijective XCD swizzle; NCHA = 512 divisible by 8: blk = xcd*64 + orig/8
    const int orig = blockIdx.x;
    const int blk  = (orig & 7) * (NCHA >> 3) + (orig >> 3);
    const int c0   = blk * 160;

    if (tid < BATCH) labL[tid] = labels[tid];

    // ---- phase 1: three passes (64 + 64 + 32 rows, 16 lanes/row) ----
    {
        const int p = tid & 15;
        #pragma unroll
        for (int h = 0; h < 3; ++h) {
            if (h < 2 || tid < 512) {
                const int c = h * 64 + (tid >> 4);       // class 0..159
                const float4* src =
                    (const float4*)(weight + (size_t)(c0 + c) * EMBED) + p;

                float4 wv[6];
                float ss = 0.f;
                #pragma unroll
                for (int i = 0; i < 6; ++i) {
                    wv[i] = src[16 * i];
                    ss += wv[i].x * wv[i].x + wv[i].y * wv[i].y
                        + wv[i].z * wv[i].z + wv[i].w * wv[i].w;
                }
                ss += __shfl_xor(ss, 1, 64);
                ss += __shfl_xor(ss, 2, 64);
                ss += __shfl_xor(ss, 4, 64);
                ss += __shfl_xor(ss, 8, 64);
                const float inv = (ss > 0.f) ? rsqrtf(ss) : 0.f;

                const int t2 = c >> 4, cl = c & 15;      // t2 in 0..9
                #pragma unroll
                for (int i = 0; i < 6; ++i) {
                    int q   = p + 16 * i;
                    int ks  = q >> 3;
                    int lgp = (q >> 1) & 3;
                    int jo  = (q & 1) * 4;
                    ushort4 o;
                    o.x = cvt_bf(wv[i].x * inv); o.y = cvt_bf(wv[i].y * inv);
                    o.z = cvt_bf(wv[i].z * inv); o.w = cvt_bf(wv[i].w * inv);
                    int ei = (((t2 * 12 + ks) * 64) + cl + 16 * lgp) * 8 + jo;
                    ei ^= (lgp & 3) << 4;
                    *(ushort4*)&Bl[ei] = o;
                }
            }
            __builtin_amdgcn_sched_barrier(0);
        }
    }
    __syncthreads();

    // ---- phase 2: MFMA, 16 waves x (2 Mtiles x 10 Ntiles), K=384 ----
    const int wid = tid >> 6, l = tid & 63;
    const int lr  = l & 15,  lg = l >> 4;
    const int bxo = (lg & 3) << 4;

    const ushort* abase = eP + ((size_t)(wid * 2) * 12 * 64 + l) * 8;

    f32x4 acc[2][10];
    #pragma unroll
    for (int mt = 0; mt < 2; ++mt)
        #pragma unroll
        for (int nt = 0; nt < 10; ++nt)
            acc[mt][nt] = (f32x4){0.f, 0.f, 0.f, 0.f};

    #pragma unroll
    for (int ks = 0; ks < 12; ++ks) {
        bf16x8 a0 = *(const bf16x8*)(abase + (0 * 12 + ks) * 512);
        bf16x8 a1 = *(const bf16x8*)(abase + (1 * 12 + ks) * 512);
        #pragma unroll
        for (int nt = 0; nt < 10; ++nt) {
            int ei = ((nt * 12 + ks) * 64 + l) * 8;
            bf16x8 b = *(const bf16x8*)&Bl[ei ^ bxo];
            acc[0][nt] = __builtin_amdgcn_mfma_f32_16x16x32_bf16(
                a0, b, acc[0][nt], 0, 0, 0);
            acc[1][nt] = __builtin_amdgcn_mfma_f32_16x16x32_bf16(
                a1, b, acc[1][nt], 0, 0, 0);
        }
    }

    // ---- phase 3: fixed-max LSE over 10 nt + rare margin fixup ----
    #pragma unroll
    for (int mt = 0; mt < 2; ++mt) {
        #pragma unroll
        for (int rg = 0; rg < 4; ++rg) {
            const int r   = wid * 32 + mt * 16 + lg * 4 + rg;
            const int lab = labL[r];
            float acc4 = 0.f;
            #pragma unroll
            for (int nt = 0; nt < 10; ++nt) {
                float cv = __builtin_amdgcn_fmed3f(acc[mt][nt][rg],
                                                   -1.f + EPS_, 1.f - EPS_);
                acc4 += exp2f(fmaf(cv, SK1_, -BIGZ_));
            }
            int off = lab - c0;
            if (((unsigned)off < 160u) && ((off & 15) == lr)) {
                int ntl = off >> 4;
                float cv = acc[mt][0][rg];
                #pragma unroll
                for (int nt = 1; nt < 10; ++nt)
                    cv = (ntl == nt) ? acc[mt][nt][rg] : cv;
                cv = __builtin_amdgcn_fmed3f(cv, -1.f + EPS_, 1.f - EPS_);
                float plain = exp2f(fmaf(cv, SK1_, -BIGZ_));
                float zm;
                if (cv > TH_) {
                    float sv = sqrtf(fmaxf(1.f - cv * cv, 0.f));
                    zm = S_SCALE * (cv * COS_M_ - sv * SIN_M_);
                } else {
                    zm = S_SCALE * (cv - MM_);
                }
                acc4 += exp2f(fmaf(zm, LOG2E_, -BIGZ_)) - plain;
                zlabel[r] = zm;
            }
            acc4 += __shfl_xor(acc4, 1, 64);
            acc4 += __shfl_xor(acc4, 2, 64);
            acc4 += __shfl_xor(acc4, 4, 64);
            acc4 += __shfl_xor(acc4, 8, 64);
            if (lr == 0) psum[(size_t)blk * BATCH + r] = acc4;
        }
    }
}

// ---------------------------------------------------------------------------
// Kernel B: CT=80 fused (r23-verbatim body) for classes 81920..99999.
// 226 blocks (< 1 round); single-pass 8-lane stage, acc[2][5].
// ---------------------------------------------------------------------------
__global__ __launch_bounds__(1024, 4)
void arc_fused80(const ushort* __restrict__ eP, const int* __restrict__ labels,
                 const float* __restrict__ weight,
                 float* __restrict__ psum, float* __restrict__ zlabel)
{
    __shared__ ushort Bl[5 * 12 * 512];            // 61440 B
    __shared__ int    labL[BATCH];

    const int tid = threadIdx.x;

    // bijective XCD swizzle for NCHB = 226 (qq=28, rr=2)
    const int orig = blockIdx.x;
    const int xcd  = orig & 7;
    const int qq   = NCHB >> 3, rr = NCHB & 7;
    const int blk  = (xcd < rr ? xcd * (qq + 1)
                               : rr * (qq + 1) + (xcd - rr) * qq) + (orig >> 3);
    const int c0   = CB_ + blk * 80;

    if (tid < BATCH) labL[tid] = labels[tid];

    // ---- phase 1: single pass, 8 lanes/row, rows 0..79 (tid < 640) ----
    if (tid < 640) {
        const int c = tid >> 3;
        const int p = tid & 7;
        const float4* src = (const float4*)(weight + (size_t)(c0 + c) * EMBED) + p;

        float4 wv[12];
        float ss = 0.f;
        #pragma unroll
        for (int i = 0; i < 12; ++i) {
            wv[i] = src[8 * i];
            ss += wv[i].x * wv[i].x + wv[i].y * wv[i].y
                + wv[i].z * wv[i].z + wv[i].w * wv[i].w;
        }
        ss += __shfl_xor(ss, 1, 64);
        ss += __shfl_xor(ss, 2, 64);
        ss += __shfl_xor(ss, 4, 64);
        const float inv = (ss > 0.f) ? rsqrtf(ss) : 0.f;

        const int t2 = c >> 4, cl = c & 15;
        #pragma unroll
        for (int i = 0; i < 12; ++i) {
            int q   = p + 8 * i;
            int ks  = q >> 3;
            int lgp = (q >> 1) & 3;
            int jo  = (q & 1) * 4;
            ushort4 o;
            o.x = cvt_bf(wv[i].x * inv); o.y = cvt_bf(wv[i].y * inv);
            o.z = cvt_bf(wv[i].z * inv); o.w = cvt_bf(wv[i].w * inv);
            int ei = (((t2 * 12 + ks) * 64) + cl + 16 * lgp) * 8 + jo;
            ei ^= (lgp & 3) << 4;
            *(ushort4*)&Bl[ei] = o;
        }
    }
    __syncthreads();

    // ---- phase 2: MFMA, 16 waves x (2 Mtiles x 5 Ntiles), K=384 ----
    const int wid = tid >> 6, l = tid & 63;
    const int lr  = l & 15,  lg = l >> 4;
    const int bxo = (lg & 3) << 4;

    const ushort* abase = eP + ((size_t)(wid * 2) * 12 * 64 + l) * 8;

    f32x4 acc[2][5];
    #pragma unroll
    for (int mt = 0; mt < 2; ++mt)
        #pragma unroll
        for (int nt = 0; nt < 5; ++nt)
            acc[mt][nt] = (f32x4){0.f, 0.f, 0.f, 0.f};

    #pragma unroll
    for (int ks = 0; ks < 12; ++ks) {
        bf16x8 a0 = *(const bf16x8*)(abase + (0 * 12 + ks) * 512);
        bf16x8 a1 = *(const bf16x8*)(abase + (1 * 12 + ks) * 512);
        #pragma unroll
        for (int nt = 0; nt < 5; ++nt) {
            int ei = ((nt * 12 + ks) * 64 + l) * 8;
            bf16x8 b = *(const bf16x8*)&Bl[ei ^ bxo];
            acc[0][nt] = __builtin_amdgcn_mfma_f32_16x16x32_bf16(
                a0, b, acc[0][nt], 0, 0, 0);
            acc[1][nt] = __builtin_amdgcn_mfma_f32_16x16x32_bf16(
                a1, b, acc[1][nt], 0, 0, 0);
        }
    }

    // ---- phase 3: fixed-max LSE over 5 nt + rare margin fixup ----
    #pragma unroll
    for (int mt = 0; mt < 2; ++mt) {
        #pragma unroll
        for (int rg = 0; rg < 4; ++rg) {
            const int r   = wid * 32 + mt * 16 + lg * 4 + rg;
            const int lab = labL[r];
            float acc4 = 0.f;
            #pragma unroll
            for (int nt = 0; nt < 5; ++nt) {
                float cv = __builtin_amdgcn_fmed3f(acc[mt][nt][rg],
                                                   -1.f + EPS_, 1.f - EPS_);
                acc4 += exp2f(fmaf(cv, SK1_, -BIGZ_));
            }
            int off = lab - c0;
            if (((unsigned)off < 80u) && ((off & 15) == lr)) {
                int ntl = off >> 4;
                float cv = acc[mt][0][rg];
                #pragma unroll
                for (int nt = 1; nt < 5; ++nt)
                    cv = (ntl == nt) ? acc[mt][nt][rg] : cv;
                cv = __builtin_amdgcn_fmed3f(cv, -1.f + EPS_, 1.f - EPS_);
                float plain = exp2f(fmaf(cv, SK1_, -BIGZ_));
                float zm;
                if (cv > TH_) {
                    float sv = sqrtf(fmaxf(1.f - cv * cv, 0.f));
                    zm = S_SCALE * (cv * COS_M_ - sv * SIN_M_);
                } else {
                    zm = S_SCALE * (cv - MM_);
                }
                acc4 += exp2f(fmaf(zm, LOG2E_, -BIGZ_)) - plain;
                zlabel[r] = zm;
            }
            acc4 += __shfl_xor(acc4, 1, 64);
            acc4 += __shfl_xor(acc4, 2, 64);
            acc4 += __shfl_xor(acc4, 4, 64);
            acc4 += __shfl_xor(acc4, 8, 64);
            if (lr == 0) psum[(size_t)(NCHA + blk) * BATCH + r] = acc4;
        }
    }
}

// ---------------------------------------------------------------------------
// Kernel 2: sum 738 partials per row -> row loss
// ---------------------------------------------------------------------------
__global__ __launch_bounds__(256)
void arc_reduce(const float* __restrict__ psum, const float* __restrict__ zlabel,
                float* __restrict__ rowloss)
{
    const int r = blockIdx.x;
    const int tid = threadIdx.x;
    float s = 0.f;
    for (int k = tid; k < NPART; k += 256)
        s += psum[(size_t)k * BATCH + r];
    #pragma unroll
    for (int d = 1; d < 64; d <<= 1) s += __shfl_xor(s, d, 64);
    __shared__ float ssh[4];
    if ((tid & 63) == 0) ssh[tid >> 6] = s;
    __syncthreads();
    if (tid == 0) {
        float t = ssh[0] + ssh[1] + ssh[2] + ssh[3];
        rowloss[r] = LN2_ * (BIGZ_ + log2f(t)) - zlabel[r];
    }
}

// ---------------------------------------------------------------------------
// Kernel 3: mean over rows
// ---------------------------------------------------------------------------
__global__ __launch_bounds__(512)
void arc_mean(const float* __restrict__ rowloss, float* __restrict__ out)
{
    const int tid = threadIdx.x;
    float v = rowloss[tid];
    #pragma unroll
    for (int d = 1; d < 64; d <<= 1) v += __shfl_xor(v, d, 64);
    __shared__ float sv[8];
    if ((tid & 63) == 0) sv[tid >> 6] = v;
    __syncthreads();
    if (tid == 0) {
        float t = 0.f;
        #pragma unroll
        for (int w = 0; w < 8; ++w) t += sv[w];
        out[0] = t / (float)BATCH;
    }
}

extern "C" void kernel_launch(void* const* d_in, const int* in_sizes, int n_in,
                              void* d_out, int out_size, void* d_ws, size_t ws_size,
                              hipStream_t stream)
{
    (void)in_sizes; (void)n_in; (void)out_size; (void)ws_size;
    const float* emb    = (const float*)d_in[0];
    const int*   labels = (const int*)d_in[1];
    const float* weight = (const float*)d_in[2];
    float* out = (float*)d_out;

    float*  psum    = (float*)d_ws;                    // [NPART][BATCH] 1.51 MB
    float*  zlabel  = psum + (size_t)NPART * BATCH;    // [BATCH]
    float*  rowloss = zlabel + BATCH;                  // [BATCH]
    ushort* eP      = (ushort*)(rowloss + BATCH);      // packed bf16 E frags

    cvt_pack_e<<<(BATCH * EMBED / 8) / 256, 256, 0, stream>>>(emb, eP);
    arc_fused160<<<NCHA, 1024, 0, stream>>>(eP, labels, weight, psum, zlabel);
    arc_fused80<<<NCHB, 1024, 0, stream>>>(eP, labels, weight, psum, zlabel);
    arc_reduce<<<BATCH, 256, 0, stream>>>(psum, zlabel, rowloss);
    arc_mean<<<1, 512, 0, stream>>>(rowloss, out);
}